// Round 1
// baseline (74.961 us; speedup 1.0000x reference)
//
#include <hip/hip_runtime.h>
#include <hip/hip_bf16.h>

#define BB 8
#define NN 2048
#define FD 128

typedef float f32x4 __attribute__((ext_vector_type(4)));
typedef short bf16x8 __attribute__((ext_vector_type(8)));
typedef short s16x4 __attribute__((ext_vector_type(4)));

__device__ __forceinline__ short f2bf(float f) {
  union { __hip_bfloat16 h; short s; } u;
  u.h = __float2bfloat16(f);
  return u.s;
}

// ---------------- kernel 1: r = rsqrt(1 + rowsum(adj)) ----------------
__global__ __launch_bounds__(256) void k_degree(const float* __restrict__ adj,
                                                float* __restrict__ r) {
  const int row  = blockIdx.x * 4 + (threadIdx.x >> 6);
  const int lane = threadIdx.x & 63;
  const f32x4* p = reinterpret_cast<const f32x4*>(adj + (size_t)row * NN);
  float s = 0.f;
#pragma unroll
  for (int i = 0; i < 8; ++i) {
    f32x4 v = p[lane + 64 * i];
    s += (v.x + v.y) + (v.z + v.w);
  }
#pragma unroll
  for (int off = 32; off >= 1; off >>= 1) s += __shfl_xor(s, off, 64);
  if (lane == 0) r[row] = rsqrtf(1.0f + s);
}

// ---------------- kernel 2: XWs = r[m] * (X @ W) ----------------
// Writes: xwsr fp32 row-major [b][m][o]  (epilogue self-loop term)
//         bpack bf16 fragment-packed: elem (m,o) -> (m>>3)*1024 + o*8 + (m&7)
__global__ __launch_bounds__(256) void k_xw(const float* __restrict__ X,
                                            const float* __restrict__ W,
                                            const float* __restrict__ r,
                                            short* __restrict__ bpack,
                                            float* __restrict__ xwsr) {
  __shared__ __align__(16) float Xs[64][132];
  __shared__ __align__(16) float Ws[128][128];
  const int b  = blockIdx.y;
  const int m0 = blockIdx.x * 64;
  const int t  = threadIdx.x;
  {
    const f32x4* wp = reinterpret_cast<const f32x4*>(W);
    f32x4* wd = reinterpret_cast<f32x4*>(&Ws[0][0]);
#pragma unroll
    for (int i = 0; i < 16; ++i) wd[t + 256 * i] = wp[t + 256 * i];
    const f32x4* xp = reinterpret_cast<const f32x4*>(X + ((size_t)b * NN + m0) * FD);
#pragma unroll
    for (int i = 0; i < 8; ++i) {
      int slot = t + 256 * i;  // row = slot/32, col4 = slot%32
      f32x4 v = xp[slot];
      *reinterpret_cast<f32x4*>(&Xs[slot >> 5][(slot & 31) * 4]) = v;
    }
  }
  __syncthreads();
  const int ot = (t & 15) * 8;
  const int mt = (t >> 4) * 4;
  float acc[4][8];
#pragma unroll
  for (int i = 0; i < 4; ++i)
#pragma unroll
    for (int j = 0; j < 8; ++j) acc[i][j] = 0.f;

  for (int k = 0; k < 128; k += 4) {
    f32x4 xv[4];
#pragma unroll
    for (int i = 0; i < 4; ++i) xv[i] = *reinterpret_cast<const f32x4*>(&Xs[mt + i][k]);
#pragma unroll
    for (int kk = 0; kk < 4; ++kk) {
      float wv[8];
#pragma unroll
      for (int j = 0; j < 8; ++j) wv[j] = Ws[k + kk][ot + j];
#pragma unroll
      for (int i = 0; i < 4; ++i)
#pragma unroll
        for (int j = 0; j < 8; ++j) acc[i][j] = fmaf(xv[i][kk], wv[j], acc[i][j]);
    }
  }
  const int bm = b * NN + m0 + mt;
#pragma unroll
  for (int i = 0; i < 4; ++i) {
    float rm = r[bm + i];
#pragma unroll
    for (int j = 0; j < 8; ++j) acc[i][j] *= rm;
  }
#pragma unroll
  for (int i = 0; i < 4; ++i) {
    f32x4 lo = {acc[i][0], acc[i][1], acc[i][2], acc[i][3]};
    f32x4 hi = {acc[i][4], acc[i][5], acc[i][6], acc[i][7]};
    float* dst = xwsr + (size_t)(bm + i) * FD + ot;
    *reinterpret_cast<f32x4*>(dst) = lo;
    *reinterpret_cast<f32x4*>(dst + 4) = hi;
  }
  short* bp = bpack + (size_t)b * NN * FD;
  const int grp = (m0 + mt) >> 3;
  const int h   = ((m0 + mt) >> 2) & 1;
#pragma unroll
  for (int j = 0; j < 8; ++j) {
    s16x4 sv;
#pragma unroll
    for (int i = 0; i < 4; ++i) sv[i] = f2bf(acc[i][j]);
    *reinterpret_cast<s16x4*>(bp + (size_t)grp * 1024 + (ot + j) * 8 + h * 4) = sv;
  }
}

// ---------------- kernel 3: out = leaky(r[n]*((adj @ XWs) + XWs[n]) + bias) ----
// BM=64 rows/block, 4 waves split the 128 output cols (32 each).
__global__ __launch_bounds__(256) void k_gemm(const float* __restrict__ adj,
                                              const short* __restrict__ bpack,
                                              const float* __restrict__ xwsr,
                                              const float* __restrict__ r,
                                              const float* __restrict__ bias,
                                              float* __restrict__ out) {
  __shared__ __align__(16) short As[2][64 * 64];  // bf16, XOR-swizzled rows of 128B
  const int b    = blockIdx.y;
  const int n0   = blockIdx.x * 64;
  const int t    = threadIdx.x;
  const int lane = t & 63;
  const int w    = t >> 6;
  const float* adjb = adj + (size_t)b * NN * NN;
  const short* bp   = bpack + (size_t)b * NN * FD;

  f32x4 zero = {0.f, 0.f, 0.f, 0.f};
  f32x4 acc[4][2];
#pragma unroll
  for (int i = 0; i < 4; ++i)
#pragma unroll
    for (int j = 0; j < 2; ++j) acc[i][j] = zero;

  auto stage_load = [&](int k0, f32x4 (&v)[4]) {
#pragma unroll
    for (int i = 0; i < 4; ++i) {
      int slot = t + 256 * i;  // row = slot>>4 (0..63), c4 = slot&15
      v[i] = *reinterpret_cast<const f32x4*>(adjb + (size_t)(n0 + (slot >> 4)) * NN + k0 + (slot & 15) * 4);
    }
  };
  auto stage_write = [&](int buf, f32x4 (&v)[4]) {
#pragma unroll
    for (int i = 0; i < 4; ++i) {
      int slot = t + 256 * i;
      int rr = slot >> 4, c4 = slot & 15;
      s16x4 sv;
      sv[0] = f2bf(v[i][0]); sv[1] = f2bf(v[i][1]);
      sv[2] = f2bf(v[i][2]); sv[3] = f2bf(v[i][3]);
      int off = rr * 128 + ((c4 * 8) ^ ((rr & 7) << 4));
      *reinterpret_cast<s16x4*>(reinterpret_cast<char*>(&As[buf][0]) + off) = sv;
    }
  };
  auto load_bfrag = [&](int k0, bf16x8 (&bf)[2][2]) {
    const int ob = w * 32 + (lane & 15);
    const int kb = (k0 >> 3) + (lane >> 4);
#pragma unroll
    for (int kk = 0; kk < 2; ++kk)
#pragma unroll
      for (int of = 0; of < 2; ++of)
        bf[kk][of] = *reinterpret_cast<const bf16x8*>(bp + (size_t)(kb + kk * 4) * 1024 + (ob + of * 16) * 8);
  };

  f32x4 nx[4];
  bf16x8 bcur[2][2], bnext[2][2];
  stage_load(0, nx);
  stage_write(0, nx);
  load_bfrag(0, bcur);
  __syncthreads();

  for (int tile = 0; tile < 32; ++tile) {
    if (tile < 31) {
      stage_load((tile + 1) * 64, nx);
      load_bfrag((tile + 1) * 64, bnext);
    }
    const char* abase = reinterpret_cast<const char*>(&As[tile & 1][0]);
#pragma unroll
    for (int kk = 0; kk < 2; ++kk) {
      bf16x8 af[4];
#pragma unroll
      for (int rg = 0; rg < 4; ++rg) {
        int rr = rg * 16 + (lane & 15);
        int off = rr * 128 + (((kk * 32 + (lane >> 4) * 8) * 2) ^ ((rr & 7) << 4));
        af[rg] = *reinterpret_cast<const bf16x8*>(abase + off);
      }
#pragma unroll
      for (int rg = 0; rg < 4; ++rg)
#pragma unroll
        for (int of = 0; of < 2; ++of)
          acc[rg][of] = __builtin_amdgcn_mfma_f32_16x16x32_bf16(af[rg], bcur[kk][of], acc[rg][of], 0, 0, 0);
    }
    if (tile < 31) {
      stage_write((tile + 1) & 1, nx);
#pragma unroll
      for (int kk = 0; kk < 2; ++kk)
#pragma unroll
        for (int of = 0; of < 2; ++of) bcur[kk][of] = bnext[kk][of];
    }
    __syncthreads();
  }

  // epilogue: C/D layout col = lane&15, row = (lane>>4)*4 + reg
  const int col = lane & 15, rq = lane >> 4;
#pragma unroll
  for (int rg = 0; rg < 4; ++rg) {
#pragma unroll
    for (int reg = 0; reg < 4; ++reg) {
      const int n = n0 + rg * 16 + rq * 4 + reg;
      const float rn = r[b * NN + n];
      const size_t rowb = ((size_t)b * NN + n) * FD;
#pragma unroll
      for (int of = 0; of < 2; ++of) {
        const int o = w * 32 + of * 16 + col;
        float v = acc[rg][of][reg] + xwsr[rowb + o];
        v = rn * v + bias[o];
        out[rowb + o] = v > 0.f ? v : 0.01f * v;
      }
    }
  }
}

extern "C" void kernel_launch(void* const* d_in, const int* in_sizes, int n_in,
                              void* d_out, int out_size, void* d_ws, size_t ws_size,
                              hipStream_t stream) {
  (void)in_sizes; (void)n_in; (void)out_size; (void)ws_size;
  const float* X    = (const float*)d_in[0];
  const float* adj  = (const float*)d_in[1];
  const float* W    = (const float*)d_in[2];
  const float* bias = (const float*)d_in[3];
  float* out = (float*)d_out;

  char* ws = (char*)d_ws;
  float* r     = (float*)ws;                                   // 64 KB
  short* bpack = (short*)(ws + 65536);                         // 4 MB
  float* xwsr  = (float*)(ws + 65536 + (size_t)BB * NN * FD * 2); // 8 MB

  k_degree<<<dim3(BB * NN / 4), dim3(256), 0, stream>>>(adj, r);
  k_xw<<<dim3(NN / 64, BB), dim3(256), 0, stream>>>(X, W, r, bpack, xwsr);
  k_gemm<<<dim3(NN / 64, BB), dim3(256), 0, stream>>>(adj, bpack, xwsr, r, bias, out);
}

// Round 2
// 72.124 us; speedup vs baseline: 1.0393x; 1.0393x over previous
//
#include <hip/hip_runtime.h>
#include <hip/hip_bf16.h>

#define BB 8
#define NN 2048
#define FD 128

typedef float f32x4 __attribute__((ext_vector_type(4)));
typedef short bf16x8 __attribute__((ext_vector_type(8)));
typedef short s16x4 __attribute__((ext_vector_type(4)));

__device__ __forceinline__ short f2bf(float f) {
  union { __hip_bfloat16 h; short s; } u;
  u.h = __float2bfloat16(f);
  return u.s;
}

// ---------------- kernel 1: fused degree + XW + pack ----------------
// Phase A: rowsums of this block's 64 adj rows -> r (LDS + global)
// Phase B: XWs = r[m] * (X @ W); writes fp32 row-major xwsr and bf16
//          MFMA-B-fragment-packed bpack: elem (m,o) -> (m>>3)*1024 + o*8 + (m&7)
__global__ __launch_bounds__(256) void k_xw_fused(const float* __restrict__ X,
                                                  const float* __restrict__ adj,
                                                  const float* __restrict__ W,
                                                  short* __restrict__ bpack,
                                                  float* __restrict__ xwsr,
                                                  float* __restrict__ r) {
  __shared__ __align__(16) float Xs[64][132];
  __shared__ __align__(16) float Ws[128][128];
  __shared__ float Ls[64];
  const int b    = blockIdx.y;
  const int m0   = blockIdx.x * 64;
  const int t    = threadIdx.x;
  const int lane = t & 63;
  const int w    = t >> 6;

  // ---- phase A: degree rowsums (wave w owns rows m0+w*16 .. +15) ----
  {
    const float* base = adj + ((size_t)b * NN + m0 + w * 16) * NN;
    for (int rr = 0; rr < 16; ++rr) {
      const f32x4* p = reinterpret_cast<const f32x4*>(base + (size_t)rr * NN);
      float s = 0.f;
#pragma unroll
      for (int i = 0; i < 8; ++i) {
        f32x4 v = p[lane + 64 * i];
        s += (v.x + v.y) + (v.z + v.w);
      }
#pragma unroll
      for (int off = 32; off >= 1; off >>= 1) s += __shfl_xor(s, off, 64);
      if (lane == 0) {
        float rv = rsqrtf(1.0f + s);
        Ls[w * 16 + rr] = rv;
        r[b * NN + m0 + w * 16 + rr] = rv;
      }
    }
  }
  // ---- stage X, W into LDS ----
  {
    const f32x4* wp = reinterpret_cast<const f32x4*>(W);
    f32x4* wd = reinterpret_cast<f32x4*>(&Ws[0][0]);
#pragma unroll
    for (int i = 0; i < 16; ++i) wd[t + 256 * i] = wp[t + 256 * i];
    const f32x4* xp = reinterpret_cast<const f32x4*>(X + ((size_t)b * NN + m0) * FD);
#pragma unroll
    for (int i = 0; i < 8; ++i) {
      int slot = t + 256 * i;  // row = slot/32, col4 = slot%32
      f32x4 v = xp[slot];
      *reinterpret_cast<f32x4*>(&Xs[slot >> 5][(slot & 31) * 4]) = v;
    }
  }
  __syncthreads();

  // ---- phase B: 64x128 fp32 GEMM, scale rows by r, pack outputs ----
  const int ot = (t & 15) * 8;
  const int mt = (t >> 4) * 4;
  float acc[4][8];
#pragma unroll
  for (int i = 0; i < 4; ++i)
#pragma unroll
    for (int j = 0; j < 8; ++j) acc[i][j] = 0.f;

  for (int k = 0; k < 128; k += 4) {
    f32x4 xv[4];
#pragma unroll
    for (int i = 0; i < 4; ++i) xv[i] = *reinterpret_cast<const f32x4*>(&Xs[mt + i][k]);
#pragma unroll
    for (int kk = 0; kk < 4; ++kk) {
      float wv[8];
#pragma unroll
      for (int j = 0; j < 8; ++j) wv[j] = Ws[k + kk][ot + j];
#pragma unroll
      for (int i = 0; i < 4; ++i)
#pragma unroll
        for (int j = 0; j < 8; ++j) acc[i][j] = fmaf(xv[i][kk], wv[j], acc[i][j]);
    }
  }
  const int bm = b * NN + m0 + mt;
#pragma unroll
  for (int i = 0; i < 4; ++i) {
    float rm = Ls[mt + i];
#pragma unroll
    for (int j = 0; j < 8; ++j) acc[i][j] *= rm;
  }
#pragma unroll
  for (int i = 0; i < 4; ++i) {
    f32x4 lo = {acc[i][0], acc[i][1], acc[i][2], acc[i][3]};
    f32x4 hi = {acc[i][4], acc[i][5], acc[i][6], acc[i][7]};
    float* dst = xwsr + (size_t)(bm + i) * FD + ot;
    *reinterpret_cast<f32x4*>(dst) = lo;
    *reinterpret_cast<f32x4*>(dst + 4) = hi;
  }
  short* bp = bpack + (size_t)b * NN * FD;
  const int grp = (m0 + mt) >> 3;
  const int h   = ((m0 + mt) >> 2) & 1;
#pragma unroll
  for (int j = 0; j < 8; ++j) {
    s16x4 sv;
#pragma unroll
    for (int i = 0; i < 4; ++i) sv[i] = f2bf(acc[i][j]);
    *reinterpret_cast<s16x4*>(bp + (size_t)grp * 1024 + (ot + j) * 8 + h * 4) = sv;
  }
}

// ---------------- kernel 2: LDS-free MFMA GEMM + fused epilogue ----------------
// out = leaky(r[n] * ((adj @ bpack) + xwsr[n]) + bias)
// 4 waves/block, wave w owns rows n0+w*16..+15, all 128 cols.
// A-frags loaded directly from global fp32 (row = n0+w*16+(lane&15),
// k = k0+(lane>>4)*8+j), converted to bf16 in-register. B-frags from L2 bpack.
// No LDS, no barriers; 2-step-deep named prefetch slots.
__global__ __launch_bounds__(256) void k_gemm2(const float* __restrict__ adj,
                                               const short* __restrict__ bpack,
                                               const float* __restrict__ xwsr,
                                               const float* __restrict__ r,
                                               const float* __restrict__ bias,
                                               float* __restrict__ out) {
  const int b    = blockIdx.y;
  const int n0   = blockIdx.x * 64;
  const int t    = threadIdx.x;
  const int lane = t & 63;
  const int w    = t >> 6;
  const int rowloc = w * 16 + (lane & 15);
  const float* ap  = adj + ((size_t)b * NN + n0 + rowloc) * NN + (lane >> 4) * 8;
  const short* bpb = bpack + (size_t)b * NN * FD + (size_t)(lane >> 4) * 1024 + (lane & 15) * 8;

  f32x4 acc[8];
#pragma unroll
  for (int i = 0; i < 8; ++i) acc[i] = (f32x4){0.f, 0.f, 0.f, 0.f};

  f32x4 aA[2], aB[2];
  bf16x8 bA[8], bB[8];

  auto loadA = [&](int ks, f32x4 (&d)[2]) {
    const f32x4* p = reinterpret_cast<const f32x4*>(ap + ks * 32);
    d[0] = p[0];
    d[1] = p[1];
  };
  auto loadB = [&](int ks, bf16x8 (&d)[8]) {
    const short* p = bpb + (size_t)ks * 4096;
#pragma unroll
    for (int ct = 0; ct < 8; ++ct)
      d[ct] = *reinterpret_cast<const bf16x8*>(p + ct * 128);
  };
  auto step = [&](f32x4 (&sa)[2], bf16x8 (&sb)[8]) {
    bf16x8 af;
#pragma unroll
    for (int i = 0; i < 4; ++i) { af[i] = f2bf(sa[0][i]); af[4 + i] = f2bf(sa[1][i]); }
#pragma unroll
    for (int ct = 0; ct < 8; ++ct)
      acc[ct] = __builtin_amdgcn_mfma_f32_16x16x32_bf16(af, sb[ct], acc[ct], 0, 0, 0);
  };

  loadA(0, aA); loadB(0, bA);
  loadA(1, aB); loadB(1, bB);
  for (int ks = 0; ks < 64; ks += 2) {
    step(aA, bA);
    if (ks + 2 < 64) { loadA(ks + 2, aA); loadB(ks + 2, bA); }
    step(aB, bB);
    if (ks + 3 < 64) { loadA(ks + 3, aB); loadB(ks + 3, bB); }
  }

  // epilogue: C/D layout col = lane&15, row = (lane>>4)*4 + reg
  const int col = lane & 15, rq = lane >> 4;
  const float* xr = xwsr + ((size_t)b * NN + n0 + w * 16) * FD;
  float* ob = out + ((size_t)b * NN + n0 + w * 16) * FD;
#pragma unroll
  for (int reg = 0; reg < 4; ++reg) {
    const int rloc = rq * 4 + reg;  // 0..15 within the wave's row strip
    const float rn = r[b * NN + n0 + w * 16 + rloc];
#pragma unroll
    for (int ct = 0; ct < 8; ++ct) {
      const int o = ct * 16 + col;
      float v = acc[ct][reg] + xr[(size_t)rloc * FD + o];
      v = rn * v + bias[o];
      ob[(size_t)rloc * FD + o] = v > 0.f ? v : 0.01f * v;
    }
  }
}

extern "C" void kernel_launch(void* const* d_in, const int* in_sizes, int n_in,
                              void* d_out, int out_size, void* d_ws, size_t ws_size,
                              hipStream_t stream) {
  (void)in_sizes; (void)n_in; (void)out_size; (void)ws_size;
  const float* X    = (const float*)d_in[0];
  const float* adj  = (const float*)d_in[1];
  const float* W    = (const float*)d_in[2];
  const float* bias = (const float*)d_in[3];
  float* out = (float*)d_out;

  char* ws = (char*)d_ws;
  float* r     = (float*)ws;                                      // 64 KB
  short* bpack = (short*)(ws + 65536);                            // 4 MB
  float* xwsr  = (float*)(ws + 65536 + (size_t)BB * NN * FD * 2); // 8 MB

  k_xw_fused<<<dim3(NN / 64, BB), dim3(256), 0, stream>>>(X, adj, W, bpack, xwsr, r);
  k_gemm2<<<dim3(NN / 64, BB), dim3(256), 0, stream>>>(adj, bpack, xwsr, r, bias, out);
}